// Round 11
// baseline (104.050 us; speedup 1.0000x reference)
//
#include <hip/hip_runtime.h>
#include <stdint.h>

#define NBL 8
#define MBS 512
#define CIN 1024
#define UQ  1024

// ---- Cl(3,0) ~ M2(C) tables (e_i -> Pauli sigma_i), verified by hand ----
// X entries (Re,Im) as combos of x blade-blocks ['','1','2','3','12','13','23','123']:
// v0=X11re=x0+x3  v1=X12re=x1-x13  v2=X21re=x1+x13  v3=X22re=x0-x3
// v4=X11im=x12+x123 v5=X12im=-x2+x23 v6=X21im=x2+x23 v7=X22im=-x12+x123
// variants 8..11 = -(v4..v7)   (negated Im copies, for Re-dest pairings)
__device__ __constant__ int   c_xs0[8] = {0,1,1,0,4,2,2,4};
__device__ __constant__ int   c_xs1[8] = {3,5,5,3,7,6,6,7};
__device__ __constant__ float c_xc0[8] = {1,1,1,1,1,-1,1,-1};
__device__ __constant__ float c_xc1[8] = {1,-1,1,-1,1,1,1,1};
// W variants identical structure, scaled by 0.5 (folds the inverse-map 1/2)
__device__ __constant__ float c_wc0[8] = {0.5f,0.5f,0.5f,0.5f,0.5f,-0.5f,0.5f,-0.5f};
__device__ __constant__ float c_wc1[8] = {0.5f,-0.5f,0.5f,-0.5f,0.5f,0.5f,0.5f,0.5f};
// Dest d in [O11re,O11im,O12re,O12im,O21re,O21im,O22re,O22im]: 4 K-segments (a,b)
__device__ __constant__ int c_sa[8][4] = {
  {0,8,1,9},{0,4,1,5},{0,8,1,9},{0,4,1,5},
  {2,10,3,11},{2,6,3,7},{2,10,3,11},{2,6,3,7}};
__device__ __constant__ int c_sb[8][4] = {
  {0,4,2,6},{4,0,6,2},{1,5,3,7},{5,1,7,3},
  {0,4,2,6},{4,0,6,2},{1,5,3,7},{5,1,7,3}};
// Dest -> two blade-output row-blocks with signs (1/2 already in W)
__device__ __constant__ int   c_eb0[8] = {0,4,1,2,1,2,0,4};
__device__ __constant__ float c_es0[8] = {1,1,1,-1,1,1,1,-1};
__device__ __constant__ int   c_eb1[8] = {3,7,5,6,5,6,3,7};
__device__ __constant__ float c_es1[8] = {1,1,-1,1,1,1,-1,1};

// original Cayley tables (fallback path only)
__device__ __constant__ int c_sigma[8][8] = {
  {0,1,2,3,4,5,6,7},{1,0,4,5,2,3,7,6},{2,4,0,6,1,7,3,5},{3,5,6,0,7,1,2,4},
  {4,2,1,7,0,6,5,3},{5,3,7,1,6,0,4,2},{6,7,3,2,5,4,0,1},{7,6,5,4,3,2,1,0}};
__device__ __constant__ int c_sg[8][8] = {
  {1,1,1,1,1,1,1,1},{1,1,1,1,1,1,1,1},{1,-1,1,1,-1,-1,1,-1},{1,-1,-1,1,1,-1,-1,1},
  {-1,1,-1,-1,1,1,-1,1},{-1,1,1,-1,-1,1,1,-1},{-1,-1,1,-1,1,-1,1,1},{-1,-1,1,-1,1,-1,1,1}};

typedef short bf16x8 __attribute__((ext_vector_type(8)));
typedef float f32x4 __attribute__((ext_vector_type(4)));

__device__ __forceinline__ uint32_t f2bf(float f) {
  uint32_t u = __float_as_uint(f);
  return (u + 0x7fffu + ((u >> 16) & 1u)) >> 16;  // RNE
}
__device__ __forceinline__ uint32_t pk2(float lo, float hi) {
  return f2bf(lo) | (f2bf(hi) << 16);
}

// Xv[v 0..11][chunk 0..127][row 0..511][8]  (chunk c = k 8c..8c+7), bf16
__global__ void cvt_x_kernel(const float* __restrict__ x, uint4* __restrict__ xv) {
  __shared__ uint4 t16[32 * 33];
  const int tid = threadIdx.x;           // 256
  const int tx = tid & 31, ty = tid >> 5;
  const int v  = blockIdx.x >> 2;        // variant 0..7
  const int cb = blockIdx.x & 3;         // chunk-block
  const int m0 = blockIdx.y * 32;        // row-block
  const int s0 = c_xs0[v] * MBS, s1 = c_xs1[v] * MBS;
  const float c0 = c_xc0[v], c1 = c_xc1[v];
#pragma unroll
  for (int r = 0; r < 4; ++r) {
    const int m = m0 + ty + r * 8;
    const float* pa = x + (size_t)(s0 + m) * CIN + cb * 256 + tx * 8;
    const float* pb = x + (size_t)(s1 + m) * CIN + cb * 256 + tx * 8;
    float4 a0 = *(const float4*)pa, a1 = *(const float4*)(pa + 4);
    float4 b0 = *(const float4*)pb, b1 = *(const float4*)(pb + 4);
    float4 f0, f1;
    f0.x = c0*a0.x + c1*b0.x; f0.y = c0*a0.y + c1*b0.y;
    f0.z = c0*a0.z + c1*b0.z; f0.w = c0*a0.w + c1*b0.w;
    f1.x = c0*a1.x + c1*b1.x; f1.y = c0*a1.y + c1*b1.y;
    f1.z = c0*a1.z + c1*b1.z; f1.w = c0*a1.w + c1*b1.w;
    uint4 p;
    p.x = pk2(f0.x, f0.y); p.y = pk2(f0.z, f0.w);
    p.z = pk2(f1.x, f1.y); p.w = pk2(f1.z, f1.w);
    t16[tx * 33 + ty + r * 8] = p;
  }
  __syncthreads();
#pragma unroll
  for (int p = 0; p < 4; ++p) {
    const int slot = p * 256 + tid;
    const int cc = slot >> 5, mm = slot & 31;
    uint4 val = t16[cc * 33 + mm];
    const size_t o = (size_t)(v * 128 + cb * 32 + cc) * 512 + m0 + mm;
    xv[o] = val;
    if (v >= 4) {  // negated Im copy -> variant v+4 (8..11)
      uint4 n;
      n.x = val.x ^ 0x80008000u; n.y = val.y ^ 0x80008000u;
      n.z = val.z ^ 0x80008000u; n.w = val.w ^ 0x80008000u;
      xv[o + (size_t)4 * 65536] = n;
    }
  }
}

// Wv[v 0..7][chunk 0..127][col 0..1023][8], bf16, scaled 0.5
__global__ void cvt_w_kernel(const float* __restrict__ w, uint4* __restrict__ wv) {
  __shared__ float ta[32][65], tb[32][65];
  const int tid = threadIdx.x;  // 256
  const int tx = tid & 63, ty = tid >> 6;
  const int v  = blockIdx.x >> 4;   // variant 0..7
  const int nb = blockIdx.x & 15;   // 64-col block within 1024
  const int k0 = blockIdx.y * 32;
  const int s0c = c_xs0[v] * UQ + nb * 64;
  const int s1c = c_xs1[v] * UQ + nb * 64;
#pragma unroll
  for (int r = 0; r < 8; ++r) {
    const int kr = ty * 8 + r;
    ta[kr][tx] = w[(size_t)(k0 + kr) * 8192 + s0c + tx];
    tb[kr][tx] = w[(size_t)(k0 + kr) * 8192 + s1c + tx];
  }
  __syncthreads();
  {
    const int cc = tid >> 6;   // local chunk 0..3
    const int uu = tid & 63;
    const float c0 = c_wc0[v], c1 = c_wc1[v];
    float e[8];
#pragma unroll
    for (int q = 0; q < 8; ++q)
      e[q] = c0 * ta[cc * 8 + q][uu] + c1 * tb[cc * 8 + q][uu];
    uint4 o;
    o.x = pk2(e[0], e[1]); o.y = pk2(e[2], e[3]);
    o.z = pk2(e[4], e[5]); o.w = pk2(e[6], e[7]);
    wv[(size_t)(v * 128 + blockIdx.y * 4 + cc) * 1024 + nb * 64 + uu] = o;
  }
}

// out[r][c] = bias[(r>>9)*1024 + c]  (prefill; GEMM atomically accumulates)
__global__ void bias_fill(const float* __restrict__ bias, float4* __restrict__ out) {
  int idx = blockIdx.x * 256 + threadIdx.x;
  int row = idx >> 8;
  int c4 = idx & 255;
  int k = row >> 9;
  out[idx] = ((const float4*)(bias + k * UQ))[c4];
}

#define BAR() do { asm volatile("s_barrier" ::: "memory");                    \
                   __builtin_amdgcn_sched_barrier(0); } while (0)
#define VMW(N) asm volatile("s_waitcnt vmcnt(" #N ")" ::: "memory")

// ---- complex-block GEMM: 8 dests x K=4096, split-K=2, R10 ring-4 core ----
__global__ __launch_bounds__(256, 2) void ga_cplx(
    const uint16_t* __restrict__ xv, const uint16_t* __restrict__ wv,
    float* __restrict__ out) {
  __shared__ uint16_t lds[4][8192];  // ring: [buf][A 4096 | B 4096] = 64 KB

  const int tid  = threadIdx.x;
  const int bid  = blockIdx.x;
  const int s    = bid >> 8;          // K-split 0/1 (2 segments each)
  const int d    = (bid >> 5) & 7;    // dest O-block
  const int mt   = (bid >> 3) & 3;
  const int ut   = bid & 7;
  const int lane = tid & 63;
  const int wid  = tid >> 6;
  const int wr   = wid >> 1, wc = wid & 1;  // 2x2 waves, each 64x64 out
  const int r15  = lane & 15, hi = lane >> 4;

  const uint16_t* aB0 = xv + (size_t)c_sa[d][s * 2 + 0] * 524288;
  const uint16_t* aB1 = xv + (size_t)c_sa[d][s * 2 + 1] * 524288;
  const uint16_t* bB0 = wv + (size_t)c_sb[d][s * 2 + 0] * 1048576;
  const uint16_t* bB1 = wv + (size_t)c_sb[d][s * 2 + 1] * 1048576;

  const int hc = tid >> 7;
  const size_t mrow8 = (size_t)(mt * 128 + (tid & 127)) * 8;
  const size_t urow8 = (size_t)(ut * 128 + (tid & 127)) * 8;

  f32x4 acc[4][4];
  const f32x4 z = {0.f, 0.f, 0.f, 0.f};
#pragma unroll
  for (int a = 0; a < 4; ++a)
#pragma unroll
    for (int b = 0; b < 4; ++b) acc[a][b] = z;

  // stage step u (BK=32 = 4 chunks): 2 A + 2 B gload_lds per thread
  auto stage = [&](int u) {
    const uint16_t* pa = (u & 32) ? aB1 : aB0;
    const uint16_t* pb = (u & 32) ? bB1 : bB0;
    const int c0 = (u & 31) << 2;
    uint16_t* la = lds[u & 3];
    uint16_t* lb = lds[u & 3] + 4096;
#pragma unroll
    for (int u2 = 0; u2 < 2; ++u2) {
      const int cc = c0 + u2 * 2 + hc;
      __builtin_amdgcn_global_load_lds(
          (const __attribute__((address_space(1))) uint32_t*)(pa + (size_t)cc * 4096 + mrow8),
          (__attribute__((address_space(3))) uint32_t*)(la + (u2 * 256 + tid) * 8), 16, 0, 0);
      __builtin_amdgcn_global_load_lds(
          (const __attribute__((address_space(1))) uint32_t*)(pb + (size_t)cc * 8192 + urow8),
          (__attribute__((address_space(3))) uint32_t*)(lb + (u2 * 256 + tid) * 8), 16, 0, 0);
    }
  };

#define READF(FA, FB, RB) {                                                   \
  const uint16_t* b_ = lds[(RB)];                                             \
  _Pragma("unroll")                                                           \
  for (int f = 0; f < 4; ++f)                                                 \
    FA[f] = *(const bf16x8*)(b_ + ((hi << 7) + wr * 64 + f * 16 + r15) * 8);  \
  _Pragma("unroll")                                                           \
  for (int g = 0; g < 4; ++g)                                                 \
    FB[g] = *(const bf16x8*)(b_ + 4096 + ((hi << 7) + wc * 64 + g * 16 + r15) * 8); \
}

#define ITER(T, CA, CB, LA, LB) {                                             \
  VMW(4);                                                                     \
  BAR();                                                                      \
  stage(((T) + 3 < 63) ? (T) + 3 : 63);                                       \
  READF(LA, LB, ((((T) + 1 < 63) ? (T) + 1 : 63) & 3));                       \
  __builtin_amdgcn_sched_barrier(0);                                          \
  __builtin_amdgcn_s_setprio(1);                                              \
  _Pragma("unroll")                                                           \
  for (int f = 0; f < 4; ++f)                                                 \
    _Pragma("unroll")                                                         \
    for (int g = 0; g < 4; ++g)                                               \
      acc[f][g] = __builtin_amdgcn_mfma_f32_16x16x32_bf16(                    \
          CA[f], CB[g], acc[f][g], 0, 0, 0);                                  \
  __builtin_amdgcn_s_setprio(0);                                              \
}

  bf16x8 fCa[4], fCb[4], fNa[4], fNb[4];

  stage(0); stage(1); stage(2);
  VMW(4);
  BAR();
  READF(fCa, fCb, 0);

  for (int t = 0; t < 64; t += 2) {
    ITER(t,     fCa, fCb, fNa, fNb);
    ITER(t + 1, fNa, fNb, fCa, fCb);
  }

  // epilogue: two blade-dest atomic accumulations with signs
  const int rb0 = c_eb0[d], rb1 = c_eb1[d];
  const float es0 = c_es0[d], es1 = c_es1[d];
  const int row0 = mt * 128 + wr * 64;
  const int col0 = ut * 128 + wc * 64;
#pragma unroll
  for (int g = 0; g < 4; ++g) {
    const int col = col0 + g * 16 + r15;
#pragma unroll
    for (int f = 0; f < 4; ++f) {
      const int r0 = row0 + f * 16 + hi * 4;
#pragma unroll
      for (int r = 0; r < 4; ++r) {
        const float val = acc[f][g][r];
        unsafeAtomicAdd(&out[(size_t)(rb0 * MBS + r0 + r) * UQ + col], es0 * val);
        unsafeAtomicAdd(&out[(size_t)(rb1 * MBS + r0 + r) * UQ + col], es1 * val);
      }
    }
  }
}

// Fallback (ws too small): correct fp32 path, slow.
__global__ void ga_naive(const float* __restrict__ x, const float* __restrict__ w,
                         const float* __restrict__ bias, float* __restrict__ out) {
  int col = blockIdx.x * 256 + threadIdx.x;
  int row = blockIdx.y;
  int k = row >> 9, m = row & 511;
  float acc = bias[k * UQ + col];
  for (int i = 0; i < 8; ++i) {
    int j = c_sigma[i][k];
    float s = (float)c_sg[i][k];
    const float* xr = x + (size_t)(i * MBS + m) * CIN;
    const float* wc = w + (size_t)j * UQ + col;
    float a = 0.f;
    for (int c = 0; c < CIN; ++c) a = fmaf(xr[c], wc[(size_t)c * (NBL * UQ)], a);
    acc = fmaf(s, a, acc);
  }
  out[(size_t)row * UQ + col] = acc;
}

extern "C" void kernel_launch(void* const* d_in, const int* in_sizes, int n_in,
                              void* d_out, int out_size, void* d_ws, size_t ws_size,
                              hipStream_t stream) {
  const float* x    = (const float*)d_in[0];   // 4096*1024
  const float* W    = (const float*)d_in[1];   // 1024*8192
  const float* bias = (const float*)d_in[2];   // 8192
  float* out = (float*)d_out;                  // 4096*1024

  const size_t need = 28u * 1024u * 1024u;     // Xv 12MB + Wv 16MB
  if (ws_size < need) {
    ga_naive<<<dim3(4, 4096), dim3(256), 0, stream>>>(x, W, bias, out);
    return;
  }

  uint16_t* xv = (uint16_t*)d_ws;              // 12 * 524288 u16
  uint16_t* wv = xv + 6291456;                 // 8 * 1048576 u16

  cvt_x_kernel<<<dim3(32, 16), dim3(256), 0, stream>>>(x, (uint4*)xv);
  cvt_w_kernel<<<dim3(128, 32), dim3(256), 0, stream>>>(W, (uint4*)wv);
  bias_fill<<<dim3(4096), dim3(256), 0, stream>>>(bias, (float4*)out);
  ga_cplx<<<dim3(512), dim3(256), 0, stream>>>(xv, wv, out);
}

// Round 12
// 66.026 us; speedup vs baseline: 1.5759x; 1.5759x over previous
//
#include <hip/hip_runtime.h>
#include <stdint.h>

#define NBL 8
#define MBS 512
#define CIN 1024
#define UQ  1024

// ---- Cl(3,0) ~ M2(C) tables (e_i -> Pauli sigma_i), HW-verified in R11 ----
__device__ __constant__ int   c_xs0[8] = {0,1,1,0,4,2,2,4};
__device__ __constant__ int   c_xs1[8] = {3,5,5,3,7,6,6,7};
__device__ __constant__ float c_xc0[8] = {1,1,1,1,1,-1,1,-1};
__device__ __constant__ float c_xc1[8] = {1,-1,1,-1,1,1,1,1};
__device__ __constant__ float c_wc0[8] = {0.5f,0.5f,0.5f,0.5f,0.5f,-0.5f,0.5f,-0.5f};
__device__ __constant__ float c_wc1[8] = {0.5f,-0.5f,0.5f,-0.5f,0.5f,0.5f,0.5f,0.5f};
__device__ __constant__ int c_sa[8][4] = {
  {0,8,1,9},{0,4,1,5},{0,8,1,9},{0,4,1,5},
  {2,10,3,11},{2,6,3,7},{2,10,3,11},{2,6,3,7}};
__device__ __constant__ int c_sb[8][4] = {
  {0,4,2,6},{4,0,6,2},{1,5,3,7},{5,1,7,3},
  {0,4,2,6},{4,0,6,2},{1,5,3,7},{5,1,7,3}};
// dest -> two blade outputs (atomic path)
__device__ __constant__ int   c_eb0[8] = {0,4,1,2,1,2,0,4};
__device__ __constant__ float c_es0[8] = {1,1,1,-1,1,1,1,-1};
__device__ __constant__ int   c_eb1[8] = {3,7,5,6,5,6,3,7};
__device__ __constant__ float c_es1[8] = {1,1,-1,1,1,1,-1,1};

// original Cayley tables (naive fallback only)
__device__ __constant__ int c_sigma[8][8] = {
  {0,1,2,3,4,5,6,7},{1,0,4,5,2,3,7,6},{2,4,0,6,1,7,3,5},{3,5,6,0,7,1,2,4},
  {4,2,1,7,0,6,5,3},{5,3,7,1,6,0,4,2},{6,7,3,2,5,4,0,1},{7,6,5,4,3,2,1,0}};
__device__ __constant__ int c_sg[8][8] = {
  {1,1,1,1,1,1,1,1},{1,1,1,1,1,1,1,1},{1,-1,1,1,-1,-1,1,-1},{1,-1,-1,1,1,-1,-1,1},
  {-1,1,-1,-1,1,1,-1,1},{-1,1,1,-1,-1,1,1,-1},{-1,-1,1,-1,1,-1,1,1},{-1,-1,1,-1,1,-1,1,1}};

typedef short bf16x8 __attribute__((ext_vector_type(8)));
typedef float f32x4 __attribute__((ext_vector_type(4)));

__device__ __forceinline__ uint32_t f2bf(float f) {
  uint32_t u = __float_as_uint(f);
  return (u + 0x7fffu + ((u >> 16) & 1u)) >> 16;  // RNE
}
__device__ __forceinline__ uint32_t pk2(float lo, float hi) {
  return f2bf(lo) | (f2bf(hi) << 16);
}

// Xv[v 0..11][chunk 0..127][row 0..511][8], bf16
__global__ void cvt_x_kernel(const float* __restrict__ x, uint4* __restrict__ xv) {
  __shared__ uint4 t16[32 * 33];
  const int tid = threadIdx.x;           // 256
  const int tx = tid & 31, ty = tid >> 5;
  const int v  = blockIdx.x >> 2;
  const int cb = blockIdx.x & 3;
  const int m0 = blockIdx.y * 32;
  const int s0 = c_xs0[v] * MBS, s1 = c_xs1[v] * MBS;
  const float c0 = c_xc0[v], c1 = c_xc1[v];
#pragma unroll
  for (int r = 0; r < 4; ++r) {
    const int m = m0 + ty + r * 8;
    const float* pa = x + (size_t)(s0 + m) * CIN + cb * 256 + tx * 8;
    const float* pb = x + (size_t)(s1 + m) * CIN + cb * 256 + tx * 8;
    float4 a0 = *(const float4*)pa, a1 = *(const float4*)(pa + 4);
    float4 b0 = *(const float4*)pb, b1 = *(const float4*)(pb + 4);
    float4 f0, f1;
    f0.x = c0*a0.x + c1*b0.x; f0.y = c0*a0.y + c1*b0.y;
    f0.z = c0*a0.z + c1*b0.z; f0.w = c0*a0.w + c1*b0.w;
    f1.x = c0*a1.x + c1*b1.x; f1.y = c0*a1.y + c1*b1.y;
    f1.z = c0*a1.z + c1*b1.z; f1.w = c0*a1.w + c1*b1.w;
    uint4 p;
    p.x = pk2(f0.x, f0.y); p.y = pk2(f0.z, f0.w);
    p.z = pk2(f1.x, f1.y); p.w = pk2(f1.z, f1.w);
    t16[tx * 33 + ty + r * 8] = p;
  }
  __syncthreads();
#pragma unroll
  for (int p = 0; p < 4; ++p) {
    const int slot = p * 256 + tid;
    const int cc = slot >> 5, mm = slot & 31;
    uint4 val = t16[cc * 33 + mm];
    const size_t o = (size_t)(v * 128 + cb * 32 + cc) * 512 + m0 + mm;
    xv[o] = val;
    if (v >= 4) {
      uint4 n;
      n.x = val.x ^ 0x80008000u; n.y = val.y ^ 0x80008000u;
      n.z = val.z ^ 0x80008000u; n.w = val.w ^ 0x80008000u;
      xv[o + (size_t)4 * 65536] = n;
    }
  }
}

// Wv[v 0..7][chunk 0..127][col 0..1023][8], bf16, scaled 0.5
__global__ void cvt_w_kernel(const float* __restrict__ w, uint4* __restrict__ wv) {
  __shared__ float ta[32][65], tb[32][65];
  const int tid = threadIdx.x;  // 256
  const int tx = tid & 63, ty = tid >> 6;
  const int v  = blockIdx.x >> 4;
  const int nb = blockIdx.x & 15;
  const int k0 = blockIdx.y * 32;
  const int s0c = c_xs0[v] * UQ + nb * 64;
  const int s1c = c_xs1[v] * UQ + nb * 64;
#pragma unroll
  for (int r = 0; r < 8; ++r) {
    const int kr = ty * 8 + r;
    ta[kr][tx] = w[(size_t)(k0 + kr) * 8192 + s0c + tx];
    tb[kr][tx] = w[(size_t)(k0 + kr) * 8192 + s1c + tx];
  }
  __syncthreads();
  {
    const int cc = tid >> 6;
    const int uu = tid & 63;
    const float c0 = c_wc0[v], c1 = c_wc1[v];
    float e[8];
#pragma unroll
    for (int q = 0; q < 8; ++q)
      e[q] = c0 * ta[cc * 8 + q][uu] + c1 * tb[cc * 8 + q][uu];
    uint4 o;
    o.x = pk2(e[0], e[1]); o.y = pk2(e[2], e[3]);
    o.z = pk2(e[4], e[5]); o.w = pk2(e[6], e[7]);
    wv[(size_t)(v * 128 + blockIdx.y * 4 + cc) * 1024 + nb * 64 + uu] = o;
  }
}

// bias prefill (atomic path only)
__global__ void bias_fill(const float* __restrict__ bias, float4* __restrict__ out) {
  int idx = blockIdx.x * 256 + threadIdx.x;
  int row = idx >> 8;
  int c4 = idx & 255;
  int k = row >> 9;
  out[idx] = ((const float4*)(bias + k * UQ))[c4];
}

// merge: out (dest-major split0 partials) + part (split1) -> blade outputs, in place.
// P[d]=P0+P1; out0=P0+P6 out3=P0-P6 out7=P1+P7 out4=P1-P7
// out1=P2+P4 out5=P4-P2 out6=P3+P5 out2=P5-P3 ; +bias.
__global__ void merge_kernel(float* out, const float* __restrict__ part,
                             const float* __restrict__ bias) {
  const int q4 = blockIdx.x * 256 + threadIdx.x;   // 0..131071 (float4 slots/dest)
  f32x4* o4 = (f32x4*)out;                          // NOT restrict: in-place
  const f32x4* p4 = (const f32x4*)part;
  const f32x4* b4 = (const f32x4*)bias;
  f32x4 P[8];
#pragma unroll
  for (int d = 0; d < 8; ++d)
    P[d] = o4[d * 131072 + q4] + p4[d * 131072 + q4];
  const int u4 = q4 & 255;
  o4[0 * 131072 + q4] = P[0] + P[6] + b4[0 * 256 + u4];
  o4[1 * 131072 + q4] = P[2] + P[4] + b4[1 * 256 + u4];
  o4[2 * 131072 + q4] = P[5] - P[3] + b4[2 * 256 + u4];
  o4[3 * 131072 + q4] = P[0] - P[6] + b4[3 * 256 + u4];
  o4[4 * 131072 + q4] = P[1] - P[7] + b4[4 * 256 + u4];
  o4[5 * 131072 + q4] = P[4] - P[2] + b4[5 * 256 + u4];
  o4[6 * 131072 + q4] = P[3] + P[5] + b4[6 * 256 + u4];
  o4[7 * 131072 + q4] = P[1] + P[7] + b4[7 * 256 + u4];
}

#define BAR() do { asm volatile("s_barrier" ::: "memory");                    \
                   __builtin_amdgcn_sched_barrier(0); } while (0)
#define VMW(N) asm volatile("s_waitcnt vmcnt(" #N ")" ::: "memory")

// ---- complex-block GEMM: 8 dests x K=4096, split-K=2, R10 ring-4 core ----
// ATOMIC=0: split0 plain-stores dest tile into out, split1 into part.
// ATOMIC=1: R11 dual-dest atomic epilogue (fallback when ws < 44 MB).
template<int ATOMIC>
__global__ __launch_bounds__(256, 2) void ga_cplx(
    const uint16_t* __restrict__ xv, const uint16_t* __restrict__ wv,
    float* __restrict__ out, float* __restrict__ part) {
  __shared__ uint16_t lds[4][8192];  // ring: [buf][A 4096 | B 4096] = 64 KB

  const int tid  = threadIdx.x;
  const int bid  = blockIdx.x;
  const int s    = bid >> 8;          // K-split 0/1
  const int d    = (bid >> 5) & 7;    // dest O-block
  const int mt   = (bid >> 3) & 3;
  const int ut   = bid & 7;
  const int lane = tid & 63;
  const int wid  = tid >> 6;
  const int wr   = wid >> 1, wc = wid & 1;
  const int r15  = lane & 15, hi = lane >> 4;

  const uint16_t* aB0 = xv + (size_t)c_sa[d][s * 2 + 0] * 524288;
  const uint16_t* aB1 = xv + (size_t)c_sa[d][s * 2 + 1] * 524288;
  const uint16_t* bB0 = wv + (size_t)c_sb[d][s * 2 + 0] * 1048576;
  const uint16_t* bB1 = wv + (size_t)c_sb[d][s * 2 + 1] * 1048576;

  const int hc = tid >> 7;
  const size_t mrow8 = (size_t)(mt * 128 + (tid & 127)) * 8;
  const size_t urow8 = (size_t)(ut * 128 + (tid & 127)) * 8;

  f32x4 acc[4][4];
  const f32x4 z = {0.f, 0.f, 0.f, 0.f};
#pragma unroll
  for (int a = 0; a < 4; ++a)
#pragma unroll
    for (int b = 0; b < 4; ++b) acc[a][b] = z;

  auto stage = [&](int u) {
    const uint16_t* pa = (u & 32) ? aB1 : aB0;
    const uint16_t* pb = (u & 32) ? bB1 : bB0;
    const int c0 = (u & 31) << 2;
    uint16_t* la = lds[u & 3];
    uint16_t* lb = lds[u & 3] + 4096;
#pragma unroll
    for (int u2 = 0; u2 < 2; ++u2) {
      const int cc = c0 + u2 * 2 + hc;
      __builtin_amdgcn_global_load_lds(
          (const __attribute__((address_space(1))) uint32_t*)(pa + (size_t)cc * 4096 + mrow8),
          (__attribute__((address_space(3))) uint32_t*)(la + (u2 * 256 + tid) * 8), 16, 0, 0);
      __builtin_amdgcn_global_load_lds(
          (const __attribute__((address_space(1))) uint32_t*)(pb + (size_t)cc * 8192 + urow8),
          (__attribute__((address_space(3))) uint32_t*)(lb + (u2 * 256 + tid) * 8), 16, 0, 0);
    }
  };

#define READF(FA, FB, RB) {                                                   \
  const uint16_t* b_ = lds[(RB)];                                             \
  _Pragma("unroll")                                                           \
  for (int f = 0; f < 4; ++f)                                                 \
    FA[f] = *(const bf16x8*)(b_ + ((hi << 7) + wr * 64 + f * 16 + r15) * 8);  \
  _Pragma("unroll")                                                           \
  for (int g = 0; g < 4; ++g)                                                 \
    FB[g] = *(const bf16x8*)(b_ + 4096 + ((hi << 7) + wc * 64 + g * 16 + r15) * 8); \
}

#define ITER(T, CA, CB, LA, LB) {                                             \
  VMW(4);                                                                     \
  BAR();                                                                      \
  stage(((T) + 3 < 63) ? (T) + 3 : 63);                                       \
  READF(LA, LB, ((((T) + 1 < 63) ? (T) + 1 : 63) & 3));                       \
  __builtin_amdgcn_sched_barrier(0);                                          \
  __builtin_amdgcn_s_setprio(1);                                              \
  _Pragma("unroll")                                                           \
  for (int f = 0; f < 4; ++f)                                                 \
    _Pragma("unroll")                                                         \
    for (int g = 0; g < 4; ++g)                                               \
      acc[f][g] = __builtin_amdgcn_mfma_f32_16x16x32_bf16(                    \
          CA[f], CB[g], acc[f][g], 0, 0, 0);                                  \
  __builtin_amdgcn_s_setprio(0);                                              \
}

  bf16x8 fCa[4], fCb[4], fNa[4], fNb[4];

  stage(0); stage(1); stage(2);
  VMW(4);
  BAR();
  READF(fCa, fCb, 0);

  for (int t = 0; t < 64; t += 2) {
    ITER(t,     fCa, fCb, fNa, fNb);
    ITER(t + 1, fNa, fNb, fCa, fCb);
  }

  const int row0 = mt * 128 + wr * 64;
  const int col0 = ut * 128 + wc * 64;
  if constexpr (ATOMIC) {
    const int rb0 = c_eb0[d], rb1 = c_eb1[d];
    const float es0 = c_es0[d], es1 = c_es1[d];
#pragma unroll
    for (int g = 0; g < 4; ++g) {
      const int col = col0 + g * 16 + r15;
#pragma unroll
      for (int f = 0; f < 4; ++f) {
        const int r0 = row0 + f * 16 + hi * 4;
#pragma unroll
        for (int r = 0; r < 4; ++r) {
          const float val = acc[f][g][r];
          unsafeAtomicAdd(&out[(size_t)(rb0 * MBS + r0 + r) * UQ + col], es0 * val);
          unsafeAtomicAdd(&out[(size_t)(rb1 * MBS + r0 + r) * UQ + col], es1 * val);
        }
      }
    }
  } else {
    float* dst = (s ? part : out) + (size_t)d * 524288;
#pragma unroll
    for (int g = 0; g < 4; ++g) {
      const int col = col0 + g * 16 + r15;
#pragma unroll
      for (int f = 0; f < 4; ++f) {
        const int r0 = row0 + f * 16 + hi * 4;
#pragma unroll
        for (int r = 0; r < 4; ++r)
          dst[(size_t)(r0 + r) * UQ + col] = acc[f][g][r];
      }
    }
  }
}

// Fallback (ws too small): correct fp32 path, slow.
__global__ void ga_naive(const float* __restrict__ x, const float* __restrict__ w,
                         const float* __restrict__ bias, float* __restrict__ out) {
  int col = blockIdx.x * 256 + threadIdx.x;
  int row = blockIdx.y;
  int k = row >> 9, m = row & 511;
  float acc = bias[k * UQ + col];
  for (int i = 0; i < 8; ++i) {
    int j = c_sigma[i][k];
    float s = (float)c_sg[i][k];
    const float* xr = x + (size_t)(i * MBS + m) * CIN;
    const float* wc = w + (size_t)j * UQ + col;
    float a = 0.f;
    for (int c = 0; c < CIN; ++c) a = fmaf(xr[c], wc[(size_t)c * (NBL * UQ)], a);
    acc = fmaf(s, a, acc);
  }
  out[(size_t)row * UQ + col] = acc;
}

extern "C" void kernel_launch(void* const* d_in, const int* in_sizes, int n_in,
                              void* d_out, int out_size, void* d_ws, size_t ws_size,
                              hipStream_t stream) {
  const float* x    = (const float*)d_in[0];   // 4096*1024
  const float* W    = (const float*)d_in[1];   // 1024*8192
  const float* bias = (const float*)d_in[2];   // 8192
  float* out = (float*)d_out;                  // 4096*1024

  const size_t needA = 44u * 1024u * 1024u;    // Xv 12 + Wv 16 + part 16
  const size_t needB = 28u * 1024u * 1024u;    // Xv 12 + Wv 16
  if (ws_size < needB) {
    ga_naive<<<dim3(4, 4096), dim3(256), 0, stream>>>(x, W, bias, out);
    return;
  }

  uint16_t* xv = (uint16_t*)d_ws;              // 12 * 524288 u16
  uint16_t* wv = xv + 6291456;                 // 8 * 1048576 u16
  float* part  = (float*)((char*)d_ws + 29360128);  // 16 MB partials

  cvt_x_kernel<<<dim3(32, 16), dim3(256), 0, stream>>>(x, (uint4*)xv);
  cvt_w_kernel<<<dim3(128, 32), dim3(256), 0, stream>>>(W, (uint4*)wv);

  if (ws_size >= needA) {
    ga_cplx<0><<<dim3(512), dim3(256), 0, stream>>>(xv, wv, out, part);
    merge_kernel<<<dim3(512), dim3(256), 0, stream>>>(out, part, bias);
  } else {
    bias_fill<<<dim3(4096), dim3(256), 0, stream>>>(bias, (float4*)out);
    ga_cplx<1><<<dim3(512), dim3(256), 0, stream>>>(xv, wv, out, nullptr);
  }
}